// Round 20
// baseline (199.839 us; speedup 1.0000x reference)
//
#include <hip/hip_runtime.h>
#include <hip/hip_bf16.h>
#include <stdint.h>

// Problem constants: H=16 heads, D=1024, DK=512, Dh=64, Lq=2048, B=4, Lk=1024.
#define H_  16
#define D_  1024
#define DK_ 512
#define DH_ 64
#define LQ_ 2048
#define B_  4
#define LK_ 1024

typedef __attribute__((ext_vector_type(8))) short bf16x8_t;
typedef __attribute__((ext_vector_type(4))) unsigned short us4_t;
typedef __attribute__((ext_vector_type(4))) float fx4_t;
typedef __attribute__((ext_vector_type(4))) int ix4_t;
typedef __attribute__((ext_vector_type(2))) unsigned int u32x2_t;
typedef __attribute__((ext_vector_type(4))) unsigned int u32x4_t;

__device__ __forceinline__ unsigned short f2bf(float f) {
  unsigned int u = __builtin_bit_cast(unsigned int, f);
  u += 0x7fffu + ((u >> 16) & 1u);           // RNE
  return (unsigned short)(u >> 16);
}

// async global->LDS, 16B per lane; LDS dest is wave-uniform base (+lane*16 implicit)
__device__ __forceinline__ void gld16(const void* g, void* l) {
  __builtin_amdgcn_global_load_lds((const __attribute__((address_space(1))) void*)g,
                                   (__attribute__((address_space(3))) void*)l, 16, 0, 0);
}

// ---------- pre: cast2 (5120 blocks) + maskbits (1024) + wtrans4 (4096), one launch ----------
__global__ __launch_bounds__(256) void pre_k(const float* __restrict__ query,
    const float* __restrict__ key, const int* __restrict__ mask,
    const float* __restrict__ Wq, const float* __restrict__ Wk,
    const float* __restrict__ Wv, const float* __restrict__ Wc,
    unsigned short* __restrict__ queryb, unsigned short* __restrict__ keyb,
    unsigned int* __restrict__ mbits,
    unsigned short* __restrict__ WqT, unsigned short* __restrict__ WkT,
    unsigned short* __restrict__ WvT, unsigned short* __restrict__ WcT, float qscale) {
  __shared__ float tile[32][33];
  int bid = blockIdx.x, t = threadIdx.x;
  if (bid < 5120) {                       // cast role
    const float* in; unsigned short* out; float scale; int base;
    if (bid < 4096) { in = query; out = queryb; scale = qscale; base = bid; }
    else            { in = key;   out = keyb;   scale = 1.0f;   base = bid - 4096; }
    int i = (base * 256 + t) * 8;
    fx4_t a = *(const fx4_t*)(in + i);
    fx4_t b = *(const fx4_t*)(in + i + 4);
    unsigned short o[8];
    o[0] = f2bf(a[0] * scale); o[1] = f2bf(a[1] * scale);
    o[2] = f2bf(a[2] * scale); o[3] = f2bf(a[3] * scale);
    o[4] = f2bf(b[0] * scale); o[5] = f2bf(b[1] * scale);
    o[6] = f2bf(b[2] * scale); o[7] = f2bf(b[3] * scale);
    *(us4_t*)(out + i)     = *(us4_t*)&o[0];
    *(us4_t*)(out + i + 4) = *(us4_t*)&o[4];
  } else if (bid < 6144) {                // maskbits role
    int wi = (bid - 5120) * 256 + t;
    const int* src = mask + (size_t)wi * 32;
    unsigned int bits = 0;
#pragma unroll
    for (int c = 0; c < 8; ++c) {
      ix4_t v = *(const ix4_t*)(src + c * 4);
#pragma unroll
      for (int j = 0; j < 4; ++j) bits |= (v[j] ? 1u : 0u) << (c * 4 + j);
    }
    mbits[wi] = bits;
  } else {                                // wtrans role
    int u = bid - 6144;
    int z = u >> 10, rem = u & 1023;
    const float* in; unsigned short* out; int K;
    const int N = 1024;
    if (z == 0)      { in = Wq; out = WqT; K = 1024; }
    else if (z == 1) { in = Wk; out = WkT; K = 512; }
    else if (z == 2) { in = Wv; out = WvT; K = 512; }
    else             { in = Wc; out = WcT; K = 1024; }
    int n0 = (rem & 31) * 32, k0 = (rem >> 5) * 32;
    if (k0 >= K) return;
    int r = t >> 3, c = (t & 7) * 4;
    fx4_t v = *(const fx4_t*)(in + (size_t)(k0 + r) * N + n0 + c);
    tile[r][c] = v[0]; tile[r][c + 1] = v[1]; tile[r][c + 2] = v[2]; tile[r][c + 3] = v[3];
    __syncthreads();
    us4_t o;
    o[0] = f2bf(tile[c + 0][r]); o[1] = f2bf(tile[c + 1][r]);
    o[2] = f2bf(tile[c + 2][r]); o[3] = f2bf(tile[c + 3][r]);
    *(us4_t*)(out + (size_t)(n0 + r) * K + k0 + c) = o;
  }
}

// ---------- proj3: Q-proj (512 blk, mode2) + K-proj (256, mode2) + V-proj (256, mode1) ----------
__global__ __launch_bounds__(256) void proj3_k(const unsigned short* __restrict__ queryb,
    const unsigned short* __restrict__ keyb, const unsigned short* __restrict__ WqT,
    const unsigned short* __restrict__ WkT, const unsigned short* __restrict__ WvT,
    unsigned short* __restrict__ qhm, unsigned short* __restrict__ khm,
    unsigned short* __restrict__ vbuf) {
  __shared__ unsigned short Alds[2][128 * 32];
  __shared__ unsigned short Blds[2][128 * 32];
  int bid = blockIdx.x;
  const unsigned short *A, *Bt; void* C; int M, K, mode, bx, by;
  const int N = 1024;
  if (bid < 512)      { A = queryb; Bt = WqT; C = qhm;  M = 8192; K = 1024; mode = 2; bx = bid & 63;  by = bid >> 6; }
  else if (bid < 768) { A = keyb;   Bt = WkT; C = khm;  M = 4096; K = 512;  mode = 2; bx = (bid - 512) & 31; by = (bid - 512) >> 5; }
  else                { A = keyb;   Bt = WvT; C = vbuf; M = 4096; K = 512;  mode = 1; bx = (bid - 768) & 31; by = (bid - 768) >> 5; }
  int t = threadIdx.x;
  int l = t & 63, w = t >> 6;
  int g = l >> 4, qi = l & 15;
  int wr = w >> 1, wc = w & 1;
  int m0 = bx * 128, n0 = by * 128;
  int rl = l >> 2, ul = (l & 3) ^ (rl & 3);
  const unsigned short* Ag = A + (size_t)(m0 + w * 32 + rl) * K + ul * 8;
  const unsigned short* Bg = Bt + (size_t)(n0 + w * 32 + rl) * K + ul * 8;
  int qx = qi & 3;
  fx4_t acc[4][4] = {};
  int nk = K / 32;

#define GSTAGE(PAR, KS) do { \
    gld16(Ag + (size_t)(KS) * 32,          &Alds[PAR][(w * 32) * 32]); \
    gld16(Ag + (size_t)(KS) * 32 + 16 * K, &Alds[PAR][(w * 32 + 16) * 32]); \
    gld16(Bg + (size_t)(KS) * 32,          &Blds[PAR][(w * 32) * 32]); \
    gld16(Bg + (size_t)(KS) * 32 + 16 * K, &Blds[PAR][(w * 32 + 16) * 32]); \
  } while (0)

#define GCOMP(PAR) do { \
    bf16x8_t af_[4], bf_[4]; \
    _Pragma("unroll") for (int mi = 0; mi < 4; ++mi) \
      af_[mi] = *(bf16x8_t*)&Alds[PAR][(wr * 64 + mi * 16 + qi) * 32 + ((g ^ qx) * 8)]; \
    _Pragma("unroll") for (int ni = 0; ni < 4; ++ni) \
      bf_[ni] = *(bf16x8_t*)&Blds[PAR][(wc * 64 + ni * 16 + qi) * 32 + ((g ^ qx) * 8)]; \
    _Pragma("unroll") for (int mi = 0; mi < 4; ++mi) \
      _Pragma("unroll") for (int ni = 0; ni < 4; ++ni) \
        acc[mi][ni] = __builtin_amdgcn_mfma_f32_16x16x32_bf16(af_[mi], bf_[ni], acc[mi][ni], 0, 0, 0); \
  } while (0)

  GSTAGE(0, 0);
  for (int ks = 0; ks < nk; ks += 2) {
    __syncthreads();
    if (ks + 1 < nk) GSTAGE(1, ks + 1);
    GCOMP(0);
    __syncthreads();
    if (ks + 2 < nk) GSTAGE(0, ks + 2);
    GCOMP(1);
  }
#undef GSTAGE
#undef GCOMP
#pragma unroll
  for (int mi = 0; mi < 4; ++mi)
#pragma unroll
    for (int ni = 0; ni < 4; ++ni) {
      int row = m0 + wr * 64 + mi * 16 + g * 4;
      int col = n0 + wc * 64 + ni * 16 + qi;
#pragma unroll
      for (int r = 0; r < 4; ++r) {
        if (mode == 1) ((unsigned short*)C)[(size_t)(row + r) * N + col] = f2bf(acc[mi][ni][r]);
        else {
          int m = row + r;
          int bb = m & 3, qq = m >> 2, hh = col >> 6, dd = col & 63;
          ((unsigned short*)C)[(((size_t)(bb * 16 + hh) * (M >> 2)) + qq) * 64 + dd] = f2bf(acc[mi][ni][r]);
        }
      }
    }
}

// ---------- V transpose: vb (Lk*B, D) bf16 -> vbT[(b*D + n)*Lk + lk] ----------
__global__ __launch_bounds__(256) void vtrans_k(const unsigned short* __restrict__ vb,
    unsigned short* __restrict__ vbT) {
  __shared__ unsigned short tile[64][72];
  int t = threadIdx.x;
  int lk0 = blockIdx.x * 64, n0 = blockIdx.y * 64, b = blockIdx.z;
  int i = t >> 2, c = (t & 3) * 16;
  const unsigned short* src = &vb[((size_t)(lk0 + i) * B_ + b) * D_ + n0 + c];
  *(bf16x8_t*)&tile[i][c]     = *(const bf16x8_t*)src;
  *(bf16x8_t*)&tile[i][c + 8] = *(const bf16x8_t*)(src + 8);
  __syncthreads();
  unsigned short o[16];
#pragma unroll
  for (int u = 0; u < 16; ++u) o[u] = tile[c + u][i];
  unsigned short* dst = &vbT[((size_t)b * D_ + n0 + i) * LK_ + lk0 + c];
  *(bf16x8_t*)&dst[0] = *(bf16x8_t*)&o[0];
  *(bf16x8_t*)&dst[8] = *(bf16x8_t*)&o[8];
}

// ---------- opass: fused l + O. Block = (b,h,64 q-rows), 4 waves x 16 q. (r19 proven) ----------
// launch_bounds N stays 3 (N=4 -> 64-VGPR cap -> spill, r7/r10).
__global__ __launch_bounds__(256, 3) void opass_k(const unsigned short* __restrict__ qhm,
    const unsigned short* __restrict__ khm, const unsigned short* __restrict__ vbT,
    const unsigned int* __restrict__ mbits, unsigned short* __restrict__ outp,
    float* __restrict__ linv) {
  __shared__ unsigned short Kt[2][64 * 64];
  __shared__ unsigned short Vt[2][64 * 64];
  int bid = blockIdx.x;
  int xcd = bid & 7, slot = bid >> 3;         // slot 0..255
  int pr = xcd * 8 + (slot >> 5);             // (b,h): 8 pairs per XCD, 32 q-tiles each
  int qt = slot & 31;
  int b = pr >> 4, h = pr & 15;
  int bh = b * H_ + h;
  int t = threadIdx.x, w = t >> 6, l = t & 63, g = l >> 4, qi = l & 15;
  int q0 = qt * 64 + w * 16;                  // this wave's 16 q rows
  int qlo = qi & 7;

  bf16x8_t qf[2];
  {
    const unsigned short* qrow = qhm + ((size_t)bh * LQ_ + q0 + qi) * 64;
    qf[0] = *(const bf16x8_t*)(qrow + g * 8);
    qf[1] = *(const bf16x8_t*)(qrow + 32 + g * 8);
  }
  int srow = l >> 3, ssub = (l & 7) ^ srow;
  const unsigned short* kg = khm + (size_t)bh * LK_ * 64 + ssub * 8;
  const unsigned short* vg = vbT + (size_t)bh * 64 * LK_ + ssub * 8;
  const unsigned int* mr = mbits + ((size_t)b * LQ_ + q0 + qi) * 32;
  u32x4_t onesu = { 0x3F803F80u, 0x3F803F80u, 0x3F803F80u, 0x3F803F80u };
  bf16x8_t ones = __builtin_bit_cast(bf16x8_t, onesu);

#define STAGE(PAR, KT) do { \
    _Pragma("unroll") for (int i_ = 0; i_ < 2; ++i_) { \
      int rr_ = w * 16 + i_ * 8; \
      gld16(kg + (size_t)((KT) * 64 + rr_ + srow) * 64, &Kt[PAR][rr_ * 64]); \
      gld16(vg + (size_t)(rr_ + srow) * LK_ + (KT) * 64, &Vt[PAR][rr_ * 64]); \
    } } while (0)

#define OCOMP(PAR, M0) do { \
    unsigned short* Kc_ = Kt[PAR]; unsigned short* Vc_ = Vt[PAR]; \
    fx4_t z_ = {0.f, 0.f, 0.f, 0.f}; \
    _Pragma("unroll") for (int c_ = 0; c_ < 2; ++c_) { \
      fx4_t sa_[2]; \
      _Pragma("unroll") for (int kk_ = 0; kk_ < 2; ++kk_) { \
        int row_ = 32 * c_ + 16 * kk_ + qi; \
        bf16x8_t ka_ = *(bf16x8_t*)&Kc_[row_ * 64 + ((g ^ qlo) * 8)]; \
        bf16x8_t kb_ = *(bf16x8_t*)&Kc_[row_ * 64 + (((4 + g) ^ qlo) * 8)]; \
        sa_[kk_] = __builtin_amdgcn_mfma_f32_16x16x32_bf16(ka_, qf[0], z_, 0, 0, 0); \
        sa_[kk_] = __builtin_amdgcn_mfma_f32_16x16x32_bf16(kb_, qf[1], sa_[kk_], 0, 0, 0); \
      } \
      unsigned int wm_ = c_ ? (M0).y : (M0).x; \
      float pv_[8]; \
      _Pragma("unroll") for (int r_ = 0; r_ < 4; ++r_) { \
        float a_ = __builtin_amdgcn_exp2f(sa_[0][r_]); \
        float b2_ = __builtin_amdgcn_exp2f(sa_[1][r_]); \
        pv_[r_]     = ((wm_ >> (4 * g + r_)) & 1u) ? 0.f : a_; \
        pv_[4 + r_] = ((wm_ >> (16 + 4 * g + r_)) & 1u) ? 0.f : b2_; \
      } \
      unsigned int w0_, w1_, w2_, w3_; \
      asm("v_cvt_pk_bf16_f32 %0, %1, %2" : "=v"(w0_) : "v"(pv_[0]), "v"(pv_[1])); \
      asm("v_cvt_pk_bf16_f32 %0, %1, %2" : "=v"(w1_) : "v"(pv_[2]), "v"(pv_[3])); \
      asm("v_cvt_pk_bf16_f32 %0, %1, %2" : "=v"(w2_) : "v"(pv_[4]), "v"(pv_[5])); \
      asm("v_cvt_pk_bf16_f32 %0, %1, %2" : "=v"(w3_) : "v"(pv_[6]), "v"(pv_[7])); \
      u32x4_t pw_ = { w0_, w1_, w2_, w3_ }; \
      bf16x8_t pb_ = __builtin_bit_cast(bf16x8_t, pw_); \
      o_l = __builtin_amdgcn_mfma_f32_16x16x32_bf16(ones, pb_, o_l, 0, 0, 0); \
      int wo_ = 8 * (g & 1); \
      int u0_ = (((4 * c_ + (g >> 1)) ^ qlo) << 4) + wo_; \
      int u1_ = (((4 * c_ + 2 + (g >> 1)) ^ qlo) << 4) + wo_; \
      _Pragma("unroll") for (int d_ = 0; d_ < 4; ++d_) { \
        const char* vb_ = (const char*)Vc_ + (d_ * 16 + qi) * 128; \
        u32x2_t lo_ = *(const u32x2_t*)(vb_ + u0_); \
        u32x2_t hi_ = *(const u32x2_t*)(vb_ + u1_); \
        u32x4_t vv_ = { lo_[0], lo_[1], hi_[0], hi_[1] }; \
        bf16x8_t vf_ = __builtin_bit_cast(bf16x8_t, vv_); \
        o_acc[d_] = __builtin_amdgcn_mfma_f32_16x16x32_bf16(vf_, pb_, o_acc[d_], 0, 0, 0); \
      } \
    } \
  } while (0)

  STAGE(0, 0);
  uint2 mc = *(const uint2*)(mr);
  uint2 mn;
  fx4_t o_acc[4] = {};
  fx4_t o_l = {};
  for (int tu = 0; tu < 8; ++tu) {
    int tt = 2 * tu;
    __syncthreads();                            // buf0 tile tt ready
    mn = *(const uint2*)(mr + 2 * (tt + 1));
    STAGE(1, tt + 1);                           // in flight during compute
    OCOMP(0, mc);
    __syncthreads();                            // buf1 tile tt+1 ready
    if (tt + 2 < 16) {
      mc = *(const uint2*)(mr + 2 * (tt + 2));
      STAGE(0, tt + 2);
    }
    OCOMP(1, mn);
  }
#undef STAGE
#undef OCOMP
  float iv = 1.0f / o_l[0];
  if (g == 0) linv[(size_t)bh * LQ_ + q0 + qi] = iv;
#pragma unroll
  for (int d = 0; d < 4; ++d) {
    unsigned short pk[4];
#pragma unroll
    for (int r = 0; r < 4; ++r) pk[r] = f2bf(o_acc[d][r] * iv);
    *(us4_t*)&outp[((size_t)(q0 + qi) * B_ + b) * D_ + h * DH_ + d * 16 + 4 * g] = *(us4_t*)&pk[0];
  }
}

// ---------- covgem: 128-THREAD (2-wave) blocks, 16KB LDS. ----------
// cov role: bids 0..2047, each block owns a 64-k slice (dbuf 8KB x2); per wave 32q x 64k
// (r18's proven per-wave shape: 16 MFMA + 32 exp2 per head-step); barrier couples 2 waves.
// gemm role: bids 2048..4095, 64x64 tile out-projection (dispatched after -> backfill).
// Residency: LDS caps 10 blocks/CU (vs r18's 5). XCD pinning: cid = bid (r15 lesson).
__global__ __launch_bounds__(128, 2) void covgem_k(const unsigned short* __restrict__ khm,
    const unsigned short* __restrict__ qhm, const unsigned int* __restrict__ mbits,
    const float* __restrict__ linv, float* __restrict__ cov,
    const unsigned short* __restrict__ outp, const unsigned short* __restrict__ WcT,
    float* __restrict__ out) {
  __shared__ unsigned short smem[2][4096];   // 16KB total, shared by both roles
  int bid = blockIdx.x;
  int t = threadIdx.x, w = t >> 6, l = t & 63, g = l >> 4, qi = l & 15;

  if (bid >= 2048) {
    // ---- out-projection: C(8192,1024) = outp x WcT^T, K=1024, 2 waves x (32m x 64n) ----
    int gid = bid - 2048;                      // 0..2047
    const int N = 1024, K = 1024;
    int bx = gid & 127, by = gid >> 7;         // 128 m-tiles x 16 n-tiles
    int m0 = bx * 64, n0 = by * 64;
    int rl = l >> 2, ul = (l & 3) ^ (rl & 3);
    const unsigned short* Ag = outp + (size_t)(m0 + w * 32 + rl) * K + ul * 8;
    const unsigned short* Bg = WcT + (size_t)(n0 + w * 32 + rl) * K + ul * 8;
    int qx = qi & 3;
    fx4_t acc[2][4] = {};
    const int nk = K / 32;

#define GSTAGE8(PAR, KS) do { \
    gld16(Ag + (size_t)(KS) * 32,          &smem[0][(PAR) * 2048 + (w * 32) * 32]); \
    gld16(Ag + (size_t)(KS) * 32 + 16 * K, &smem[0][(PAR) * 2048 + (w * 32 + 16) * 32]); \
    gld16(Bg + (size_t)(KS) * 32,          &smem[1][(PAR) * 2048 + (w * 32) * 32]); \
    gld16(Bg + (size_t)(KS) * 32 + 16 * K, &smem[1][(PAR) * 2048 + (w * 32 + 16) * 32]); \
  } while (0)

#define GCOMP8(PAR) do { \
    bf16x8_t af_[2], bf_[4]; \
    _Pragma("unroll") for (int mi = 0; mi < 2; ++mi) \
      af_[mi] = *(bf16x8_t*)&smem[0][(PAR) * 2048 + (w * 32 + mi * 16 + qi) * 32 + ((g ^ qx) * 8)]; \
    _Pragma("unroll") for (int ni = 0; ni < 4; ++ni) \
      bf_[ni] = *(bf16x8_t*)&smem[1][(PAR) * 2048 + (ni * 16 + qi) * 32 + ((g ^ qx) * 8)]; \
    _Pragma("unroll") for (int mi = 0; mi < 2; ++mi) \
      _Pragma("unroll") for (int ni = 0; ni < 4; ++ni) \
        acc[mi][ni] = __builtin_amdgcn_mfma_f32_16x16x32_bf16(af_[mi], bf_[ni], acc[mi][ni], 0, 0, 0); \
  } while (0)

    GSTAGE8(0, 0);
    for (int ks = 0; ks < nk; ks += 2) {
      __syncthreads();
      if (ks + 1 < nk) GSTAGE8(1, ks + 1);
      GCOMP8(0);
      __syncthreads();
      if (ks + 2 < nk) GSTAGE8(0, ks + 2);
      GCOMP8(1);
    }
#undef GSTAGE8
#undef GCOMP8
#pragma unroll
    for (int mi = 0; mi < 2; ++mi)
#pragma unroll
      for (int ni = 0; ni < 4; ++ni) {
        int row = m0 + w * 32 + mi * 16 + g * 4;
        int col = n0 + ni * 16 + qi;
#pragma unroll
        for (int r = 0; r < 4; ++r)
          out[(size_t)(row + r) * N + col] = acc[mi][ni][r];
      }
    return;
  }

  // ---- covpass role: 2 waves x 32q each over a 64-k slice; dbuf; mask hoisted. ----
  int cid = bid;                              // XCD pinning preserved (cid%8 == bid%8)
  int x = cid & 7;
  int b = x >> 1, keh = x & 1;                // (b, k-half) pinned per XCD
  int rest = cid >> 3;                        // 0..255
  int ks64 = rest & 7;                        // 64-k slice within the half (0..7)
  int qt = rest >> 3;                         // 0..31
  int q0 = qt * 64;
  int qlo = qi & 7;
  int kbase = keh * 512 + ks64 * 64;
  int qA = q0 + 32 * w + qi;                  // wave w owns 32 q rows
  int qB = qA + 16;
  int srow = l >> 3, ssub = (l & 7) ^ srow;
  int wo = kbase >> 5;                        // 2 mask words cover the 64-k slice
  uint2 MWA = *(const uint2*)&mbits[((size_t)b * LQ_ + qA) * 32 + wo];
  uint2 MWB = *(const uint2*)&mbits[((size_t)b * LQ_ + qB) * 32 + wo];

#define CSTAGE(PAR, ST) do { \
    const unsigned short* kg_ = khm + (size_t)(b * H_ + (ST)) * LK_ * 64 + ssub * 8; \
    _Pragma("unroll") for (int i_ = 0; i_ < 4; ++i_) { \
      int rr_ = w * 32 + i_ * 8; \
      gld16(kg_ + (size_t)(kbase + rr_ + srow) * 64, &smem[PAR][rr_ * 64]); \
    } } while (0)

#define CGLOB(HH, QF, IV) do { \
    const unsigned short* qra_ = qhm + ((size_t)(b * H_ + (HH)) * LQ_ + qA) * 64; \
    const unsigned short* qrb_ = qra_ + 16 * 64; \
    QF[0] = *(const bf16x8_t*)(qra_ + g * 8); QF[1] = *(const bf16x8_t*)(qra_ + 32 + g * 8); \
    QF[2] = *(const bf16x8_t*)(qrb_ + g * 8); QF[3] = *(const bf16x8_t*)(qrb_ + 32 + g * 8); \
    IV[0] = linv[((size_t)b * H_ + (HH)) * LQ_ + qA]; \
    IV[1] = linv[((size_t)b * H_ + (HH)) * LQ_ + qB]; \
  } while (0)

#define CCOMP(PAR, QF, IV) do { \
    unsigned short* Kc_ = &smem[PAR][0]; \
    fx4_t z_ = {0.f, 0.f, 0.f, 0.f}; \
    _Pragma("unroll") for (int ks = 0; ks < 4; ++ks) { \
      int row_ = 16 * ks + qi; \
      bf16x8_t k0_ = *(bf16x8_t*)&Kc_[row_ * 64 + ((g ^ qlo) * 8)]; \
      bf16x8_t k1_ = *(bf16x8_t*)&Kc_[row_ * 64 + (((4 + g) ^ qlo) * 8)]; \
      __builtin_amdgcn_s_setprio(1); \
      fx4_t sA_ = __builtin_amdgcn_mfma_f32_16x16x32_bf16(k0_, QF[0], z_, 0, 0, 0); \
      sA_ = __builtin_amdgcn_mfma_f32_16x16x32_bf16(k1_, QF[1], sA_, 0, 0, 0); \
      fx4_t sB_ = __builtin_amdgcn_mfma_f32_16x16x32_bf16(k0_, QF[2], z_, 0, 0, 0); \
      sB_ = __builtin_amdgcn_mfma_f32_16x16x32_bf16(k1_, QF[3], sB_, 0, 0, 0); \
      __builtin_amdgcn_s_setprio(0); \
      unsigned int mwa_ = (ks & 2) ? MWA.y : MWA.x; \
      unsigned int mwb_ = (ks & 2) ? MWB.y : MWB.x; \
      int sh_ = (ks & 1) * 16 + 4 * g; \
      _Pragma("unroll") for (int r_ = 0; r_ < 4; ++r_) { \
        float pA_ = __builtin_amdgcn_exp2f(sA_[r_]) * IV[0]; \
        float pB_ = __builtin_amdgcn_exp2f(sB_[r_]) * IV[1]; \
        cacc[0][ks][r_] += ((mwa_ >> (sh_ + r_)) & 1u) ? 0.f : pA_; \
        cacc[1][ks][r_] += ((mwb_ >> (sh_ + r_)) & 1u) ? 0.f : pB_; \
      } \
    } \
  } while (0)

  CSTAGE(0, 0);
  bf16x8_t qc[4], qn[4];
  float ic[2], in_[2];
  fx4_t cacc[2][4] = {};
  CGLOB(0, qc, ic);
  for (int su = 0; su < 8; ++su) {            // 16 head-steps, dbuf, 2 per iter
    int st = 2 * su;
    __syncthreads();
    CSTAGE(1, st + 1);
    CGLOB(st + 1, qn, in_);
    CCOMP(0, qc, ic);
    __syncthreads();
    if (st + 2 < 16) { CSTAGE(0, st + 2); CGLOB(st + 2, qc, ic); }
    CCOMP(1, qn, in_);
  }
#undef CSTAGE
#undef CGLOB
#undef CCOMP
  int ko = kbase;
#pragma unroll
  for (int ks = 0; ks < 4; ++ks) {
    fx4_t wA = { cacc[0][ks][0] * 0.0625f, cacc[0][ks][1] * 0.0625f,
                 cacc[0][ks][2] * 0.0625f, cacc[0][ks][3] * 0.0625f };
    fx4_t wB = { cacc[1][ks][0] * 0.0625f, cacc[1][ks][1] * 0.0625f,
                 cacc[1][ks][2] * 0.0625f, cacc[1][ks][3] * 0.0625f };
    *(fx4_t*)(cov + ((size_t)b * LQ_ + qA) * LK_ + ko + ks * 16 + 4 * g) = wA;
    *(fx4_t*)(cov + ((size_t)b * LQ_ + qB) * LK_ + ko + ks * 16 + 4 * g) = wB;
  }
}

extern "C" void kernel_launch(void* const* d_in, const int* in_sizes, int n_in,
                              void* d_out, int out_size, void* d_ws, size_t ws_size,
                              hipStream_t stream) {
  (void)in_sizes; (void)n_in; (void)out_size; (void)ws_size;
  const float* query = (const float*)d_in[0];
  const float* key   = (const float*)d_in[1];
  // d_in[2] (value) intentionally unused: reference projects `key` for both K and V.
  const int* mask = (const int*)d_in[3];
  const float* Wq = (const float*)d_in[4];
  const float* Wk = (const float*)d_in[5];
  const float* Wv = (const float*)d_in[6];
  const float* Wc = (const float*)d_in[7];
  float* out = (float*)d_out;
  float* cov = out + (size_t)LQ_ * B_ * D_;

  char* p = (char*)d_ws;
  unsigned short* queryb = (unsigned short*)p; p += (size_t)LQ_ * B_ * D_ * 2;
  unsigned short* keyb   = (unsigned short*)p; p += (size_t)LK_ * B_ * DK_ * 2;
  unsigned short* WqT    = (unsigned short*)p; p += (size_t)D_ * D_ * 2;
  unsigned short* WkT    = (unsigned short*)p; p += (size_t)D_ * DK_ * 2;
  unsigned short* WvT    = (unsigned short*)p; p += (size_t)D_ * DK_ * 2;
  unsigned short* WcT    = (unsigned short*)p; p += (size_t)D_ * D_ * 2;
  unsigned short* qhm    = (unsigned short*)p; p += (size_t)LQ_ * B_ * D_ * 2;  // head-major Q
  unsigned short* khm    = (unsigned short*)p; p += (size_t)LK_ * B_ * D_ * 2;  // head-major K
  unsigned short* vbuf   = (unsigned short*)p; p += (size_t)LK_ * B_ * D_ * 2;
  unsigned short* vbT    = (unsigned short*)p; p += (size_t)LK_ * B_ * D_ * 2;
  unsigned int*   mbits  = (unsigned int*)p;   p += (size_t)B_ * LQ_ * 32 * 4;
  float*          linv   = (float*)p;          p += (size_t)B_ * H_ * LQ_ * 4;
  unsigned short* outp   = queryb;   // reuse: queryb dead after Q projection

  const float QSCALE = 0.125f * 1.44269504088896340736f;

  pre_k<<<dim3(10240), 256, 0, stream>>>(query, key, mask, Wq, Wk, Wv, Wc,
                                         queryb, keyb, mbits, WqT, WkT, WvT, WcT, QSCALE);
  proj3_k<<<dim3(1024), 256, 0, stream>>>(queryb, keyb, WqT, WkT, WvT, qhm, khm, vbuf);
  vtrans_k<<<dim3(LK_ / 64, D_ / 64, B_), 256, 0, stream>>>(vbuf, vbT);
  opass_k<<<dim3(B_ * H_ * (LQ_ / 64)), 256, 0, stream>>>(qhm, khm, vbT, mbits, outp, linv);
  covgem_k<<<dim3(4096), 128, 0, stream>>>(khm, qhm, mbits, linv, cov, outp, WcT, out);
}

// Round 21
// 184.167 us; speedup vs baseline: 1.0851x; 1.0851x over previous
//
#include <hip/hip_runtime.h>
#include <hip/hip_bf16.h>
#include <stdint.h>

// Problem constants: H=16 heads, D=1024, DK=512, Dh=64, Lq=2048, B=4, Lk=1024.
#define H_  16
#define D_  1024
#define DK_ 512
#define DH_ 64
#define LQ_ 2048
#define B_  4
#define LK_ 1024

typedef __attribute__((ext_vector_type(8))) short bf16x8_t;
typedef __attribute__((ext_vector_type(4))) unsigned short us4_t;
typedef __attribute__((ext_vector_type(4))) float fx4_t;
typedef __attribute__((ext_vector_type(4))) int ix4_t;
typedef __attribute__((ext_vector_type(2))) unsigned int u32x2_t;
typedef __attribute__((ext_vector_type(4))) unsigned int u32x4_t;

__device__ __forceinline__ unsigned short f2bf(float f) {
  unsigned int u = __builtin_bit_cast(unsigned int, f);
  u += 0x7fffu + ((u >> 16) & 1u);           // RNE
  return (unsigned short)(u >> 16);
}

// async global->LDS, 16B per lane; LDS dest is wave-uniform base (+lane*16 implicit)
__device__ __forceinline__ void gld16(const void* g, void* l) {
  __builtin_amdgcn_global_load_lds((const __attribute__((address_space(1))) void*)g,
                                   (__attribute__((address_space(3))) void*)l, 16, 0, 0);
}

// ---------- pre: cast2 (5120 blocks) + maskbits (1024) + wtrans4 (4096), one launch ----------
__global__ __launch_bounds__(256) void pre_k(const float* __restrict__ query,
    const float* __restrict__ key, const int* __restrict__ mask,
    const float* __restrict__ Wq, const float* __restrict__ Wk,
    const float* __restrict__ Wv, const float* __restrict__ Wc,
    unsigned short* __restrict__ queryb, unsigned short* __restrict__ keyb,
    unsigned int* __restrict__ mbits,
    unsigned short* __restrict__ WqT, unsigned short* __restrict__ WkT,
    unsigned short* __restrict__ WvT, unsigned short* __restrict__ WcT, float qscale) {
  __shared__ float tile[32][33];
  int bid = blockIdx.x, t = threadIdx.x;
  if (bid < 5120) {                       // cast role
    const float* in; unsigned short* out; float scale; int base;
    if (bid < 4096) { in = query; out = queryb; scale = qscale; base = bid; }
    else            { in = key;   out = keyb;   scale = 1.0f;   base = bid - 4096; }
    int i = (base * 256 + t) * 8;
    fx4_t a = *(const fx4_t*)(in + i);
    fx4_t b = *(const fx4_t*)(in + i + 4);
    unsigned short o[8];
    o[0] = f2bf(a[0] * scale); o[1] = f2bf(a[1] * scale);
    o[2] = f2bf(a[2] * scale); o[3] = f2bf(a[3] * scale);
    o[4] = f2bf(b[0] * scale); o[5] = f2bf(b[1] * scale);
    o[6] = f2bf(b[2] * scale); o[7] = f2bf(b[3] * scale);
    *(us4_t*)(out + i)     = *(us4_t*)&o[0];
    *(us4_t*)(out + i + 4) = *(us4_t*)&o[4];
  } else if (bid < 6144) {                // maskbits role
    int wi = (bid - 5120) * 256 + t;
    const int* src = mask + (size_t)wi * 32;
    unsigned int bits = 0;
#pragma unroll
    for (int c = 0; c < 8; ++c) {
      ix4_t v = *(const ix4_t*)(src + c * 4);
#pragma unroll
      for (int j = 0; j < 4; ++j) bits |= (v[j] ? 1u : 0u) << (c * 4 + j);
    }
    mbits[wi] = bits;
  } else {                                // wtrans role
    int u = bid - 6144;
    int z = u >> 10, rem = u & 1023;
    const float* in; unsigned short* out; int K;
    const int N = 1024;
    if (z == 0)      { in = Wq; out = WqT; K = 1024; }
    else if (z == 1) { in = Wk; out = WkT; K = 512; }
    else if (z == 2) { in = Wv; out = WvT; K = 512; }
    else             { in = Wc; out = WcT; K = 1024; }
    int n0 = (rem & 31) * 32, k0 = (rem >> 5) * 32;
    if (k0 >= K) return;
    int r = t >> 3, c = (t & 7) * 4;
    fx4_t v = *(const fx4_t*)(in + (size_t)(k0 + r) * N + n0 + c);
    tile[r][c] = v[0]; tile[r][c + 1] = v[1]; tile[r][c + 2] = v[2]; tile[r][c + 3] = v[3];
    __syncthreads();
    us4_t o;
    o[0] = f2bf(tile[c + 0][r]); o[1] = f2bf(tile[c + 1][r]);
    o[2] = f2bf(tile[c + 2][r]); o[3] = f2bf(tile[c + 3][r]);
    *(us4_t*)(out + (size_t)(n0 + r) * K + k0 + c) = o;
  }
}

// ---------- proj3: Q-proj (512 blk, mode2) + K-proj (256, mode2) + V-proj (256, mode1) ----------
__global__ __launch_bounds__(256) void proj3_k(const unsigned short* __restrict__ queryb,
    const unsigned short* __restrict__ keyb, const unsigned short* __restrict__ WqT,
    const unsigned short* __restrict__ WkT, const unsigned short* __restrict__ WvT,
    unsigned short* __restrict__ qhm, unsigned short* __restrict__ khm,
    unsigned short* __restrict__ vbuf) {
  __shared__ unsigned short Alds[2][128 * 32];
  __shared__ unsigned short Blds[2][128 * 32];
  int bid = blockIdx.x;
  const unsigned short *A, *Bt; void* C; int M, K, mode, bx, by;
  const int N = 1024;
  if (bid < 512)      { A = queryb; Bt = WqT; C = qhm;  M = 8192; K = 1024; mode = 2; bx = bid & 63;  by = bid >> 6; }
  else if (bid < 768) { A = keyb;   Bt = WkT; C = khm;  M = 4096; K = 512;  mode = 2; bx = (bid - 512) & 31; by = (bid - 512) >> 5; }
  else                { A = keyb;   Bt = WvT; C = vbuf; M = 4096; K = 512;  mode = 1; bx = (bid - 768) & 31; by = (bid - 768) >> 5; }
  int t = threadIdx.x;
  int l = t & 63, w = t >> 6;
  int g = l >> 4, qi = l & 15;
  int wr = w >> 1, wc = w & 1;
  int m0 = bx * 128, n0 = by * 128;
  int rl = l >> 2, ul = (l & 3) ^ (rl & 3);
  const unsigned short* Ag = A + (size_t)(m0 + w * 32 + rl) * K + ul * 8;
  const unsigned short* Bg = Bt + (size_t)(n0 + w * 32 + rl) * K + ul * 8;
  int qx = qi & 3;
  fx4_t acc[4][4] = {};
  int nk = K / 32;

#define GSTAGE(PAR, KS) do { \
    gld16(Ag + (size_t)(KS) * 32,          &Alds[PAR][(w * 32) * 32]); \
    gld16(Ag + (size_t)(KS) * 32 + 16 * K, &Alds[PAR][(w * 32 + 16) * 32]); \
    gld16(Bg + (size_t)(KS) * 32,          &Blds[PAR][(w * 32) * 32]); \
    gld16(Bg + (size_t)(KS) * 32 + 16 * K, &Blds[PAR][(w * 32 + 16) * 32]); \
  } while (0)

#define GCOMP(PAR) do { \
    bf16x8_t af_[4], bf_[4]; \
    _Pragma("unroll") for (int mi = 0; mi < 4; ++mi) \
      af_[mi] = *(bf16x8_t*)&Alds[PAR][(wr * 64 + mi * 16 + qi) * 32 + ((g ^ qx) * 8)]; \
    _Pragma("unroll") for (int ni = 0; ni < 4; ++ni) \
      bf_[ni] = *(bf16x8_t*)&Blds[PAR][(wc * 64 + ni * 16 + qi) * 32 + ((g ^ qx) * 8)]; \
    _Pragma("unroll") for (int mi = 0; mi < 4; ++mi) \
      _Pragma("unroll") for (int ni = 0; ni < 4; ++ni) \
        acc[mi][ni] = __builtin_amdgcn_mfma_f32_16x16x32_bf16(af_[mi], bf_[ni], acc[mi][ni], 0, 0, 0); \
  } while (0)

  GSTAGE(0, 0);
  for (int ks = 0; ks < nk; ks += 2) {
    __syncthreads();
    if (ks + 1 < nk) GSTAGE(1, ks + 1);
    GCOMP(0);
    __syncthreads();
    if (ks + 2 < nk) GSTAGE(0, ks + 2);
    GCOMP(1);
  }
#undef GSTAGE
#undef GCOMP
#pragma unroll
  for (int mi = 0; mi < 4; ++mi)
#pragma unroll
    for (int ni = 0; ni < 4; ++ni) {
      int row = m0 + wr * 64 + mi * 16 + g * 4;
      int col = n0 + wc * 64 + ni * 16 + qi;
#pragma unroll
      for (int r = 0; r < 4; ++r) {
        if (mode == 1) ((unsigned short*)C)[(size_t)(row + r) * N + col] = f2bf(acc[mi][ni][r]);
        else {
          int m = row + r;
          int bb = m & 3, qq = m >> 2, hh = col >> 6, dd = col & 63;
          ((unsigned short*)C)[(((size_t)(bb * 16 + hh) * (M >> 2)) + qq) * 64 + dd] = f2bf(acc[mi][ni][r]);
        }
      }
    }
}

// ---------- V transpose: vb (Lk*B, D) bf16 -> vbT[(b*D + n)*Lk + lk] ----------
__global__ __launch_bounds__(256) void vtrans_k(const unsigned short* __restrict__ vb,
    unsigned short* __restrict__ vbT) {
  __shared__ unsigned short tile[64][72];
  int t = threadIdx.x;
  int lk0 = blockIdx.x * 64, n0 = blockIdx.y * 64, b = blockIdx.z;
  int i = t >> 2, c = (t & 3) * 16;
  const unsigned short* src = &vb[((size_t)(lk0 + i) * B_ + b) * D_ + n0 + c];
  *(bf16x8_t*)&tile[i][c]     = *(const bf16x8_t*)src;
  *(bf16x8_t*)&tile[i][c + 8] = *(const bf16x8_t*)(src + 8);
  __syncthreads();
  unsigned short o[16];
#pragma unroll
  for (int u = 0; u < 16; ++u) o[u] = tile[c + u][i];
  unsigned short* dst = &vbT[((size_t)b * D_ + n0 + i) * LK_ + lk0 + c];
  *(bf16x8_t*)&dst[0] = *(bf16x8_t*)&o[0];
  *(bf16x8_t*)&dst[8] = *(bf16x8_t*)&o[8];
}

// ---------- opass: fused l + O. Block = (b,h,64 q-rows), 4 waves x 16 q. (r19 proven) ----------
// launch_bounds N stays 3 (N=4 -> 64-VGPR cap -> spill, r7/r10).
__global__ __launch_bounds__(256, 3) void opass_k(const unsigned short* __restrict__ qhm,
    const unsigned short* __restrict__ khm, const unsigned short* __restrict__ vbT,
    const unsigned int* __restrict__ mbits, unsigned short* __restrict__ outp,
    float* __restrict__ linv) {
  __shared__ unsigned short Kt[2][64 * 64];
  __shared__ unsigned short Vt[2][64 * 64];
  int bid = blockIdx.x;
  int xcd = bid & 7, slot = bid >> 3;         // slot 0..255
  int pr = xcd * 8 + (slot >> 5);             // (b,h): 8 pairs per XCD, 32 q-tiles each
  int qt = slot & 31;
  int b = pr >> 4, h = pr & 15;
  int bh = b * H_ + h;
  int t = threadIdx.x, w = t >> 6, l = t & 63, g = l >> 4, qi = l & 15;
  int q0 = qt * 64 + w * 16;                  // this wave's 16 q rows
  int qlo = qi & 7;

  bf16x8_t qf[2];
  {
    const unsigned short* qrow = qhm + ((size_t)bh * LQ_ + q0 + qi) * 64;
    qf[0] = *(const bf16x8_t*)(qrow + g * 8);
    qf[1] = *(const bf16x8_t*)(qrow + 32 + g * 8);
  }
  int srow = l >> 3, ssub = (l & 7) ^ srow;
  const unsigned short* kg = khm + (size_t)bh * LK_ * 64 + ssub * 8;
  const unsigned short* vg = vbT + (size_t)bh * 64 * LK_ + ssub * 8;
  const unsigned int* mr = mbits + ((size_t)b * LQ_ + q0 + qi) * 32;
  u32x4_t onesu = { 0x3F803F80u, 0x3F803F80u, 0x3F803F80u, 0x3F803F80u };
  bf16x8_t ones = __builtin_bit_cast(bf16x8_t, onesu);

  // 4 waves x 2KB each per matrix = full 64-row K and V tiles
#define STAGE(PAR, KT) do { \
    _Pragma("unroll") for (int i_ = 0; i_ < 2; ++i_) { \
      int rr_ = w * 16 + i_ * 8; \
      gld16(kg + (size_t)((KT) * 64 + rr_ + srow) * 64, &Kt[PAR][rr_ * 64]); \
      gld16(vg + (size_t)(rr_ + srow) * LK_ + (KT) * 64, &Vt[PAR][rr_ * 64]); \
    } } while (0)

#define OCOMP(PAR, M0) do { \
    unsigned short* Kc_ = Kt[PAR]; unsigned short* Vc_ = Vt[PAR]; \
    fx4_t z_ = {0.f, 0.f, 0.f, 0.f}; \
    _Pragma("unroll") for (int c_ = 0; c_ < 2; ++c_) { \
      fx4_t sa_[2]; \
      _Pragma("unroll") for (int kk_ = 0; kk_ < 2; ++kk_) { \
        int row_ = 32 * c_ + 16 * kk_ + qi; \
        bf16x8_t ka_ = *(bf16x8_t*)&Kc_[row_ * 64 + ((g ^ qlo) * 8)]; \
        bf16x8_t kb_ = *(bf16x8_t*)&Kc_[row_ * 64 + (((4 + g) ^ qlo) * 8)]; \
        sa_[kk_] = __builtin_amdgcn_mfma_f32_16x16x32_bf16(ka_, qf[0], z_, 0, 0, 0); \
        sa_[kk_] = __builtin_amdgcn_mfma_f32_16x16x32_bf16(kb_, qf[1], sa_[kk_], 0, 0, 0); \
      } \
      unsigned int wm_ = c_ ? (M0).y : (M0).x; \
      float pv_[8]; \
      _Pragma("unroll") for (int r_ = 0; r_ < 4; ++r_) { \
        float a_ = __builtin_amdgcn_exp2f(sa_[0][r_]); \
        float b2_ = __builtin_amdgcn_exp2f(sa_[1][r_]); \
        pv_[r_]     = ((wm_ >> (4 * g + r_)) & 1u) ? 0.f : a_; \
        pv_[4 + r_] = ((wm_ >> (16 + 4 * g + r_)) & 1u) ? 0.f : b2_; \
      } \
      unsigned int w0_, w1_, w2_, w3_; \
      asm("v_cvt_pk_bf16_f32 %0, %1, %2" : "=v"(w0_) : "v"(pv_[0]), "v"(pv_[1])); \
      asm("v_cvt_pk_bf16_f32 %0, %1, %2" : "=v"(w1_) : "v"(pv_[2]), "v"(pv_[3])); \
      asm("v_cvt_pk_bf16_f32 %0, %1, %2" : "=v"(w2_) : "v"(pv_[4]), "v"(pv_[5])); \
      asm("v_cvt_pk_bf16_f32 %0, %1, %2" : "=v"(w3_) : "v"(pv_[6]), "v"(pv_[7])); \
      u32x4_t pw_ = { w0_, w1_, w2_, w3_ }; \
      bf16x8_t pb_ = __builtin_bit_cast(bf16x8_t, pw_); \
      o_l = __builtin_amdgcn_mfma_f32_16x16x32_bf16(ones, pb_, o_l, 0, 0, 0); \
      int wo_ = 8 * (g & 1); \
      int u0_ = (((4 * c_ + (g >> 1)) ^ qlo) << 4) + wo_; \
      int u1_ = (((4 * c_ + 2 + (g >> 1)) ^ qlo) << 4) + wo_; \
      _Pragma("unroll") for (int d_ = 0; d_ < 4; ++d_) { \
        const char* vb_ = (const char*)Vc_ + (d_ * 16 + qi) * 128; \
        u32x2_t lo_ = *(const u32x2_t*)(vb_ + u0_); \
        u32x2_t hi_ = *(const u32x2_t*)(vb_ + u1_); \
        u32x4_t vv_ = { lo_[0], lo_[1], hi_[0], hi_[1] }; \
        bf16x8_t vf_ = __builtin_bit_cast(bf16x8_t, vv_); \
        o_acc[d_] = __builtin_amdgcn_mfma_f32_16x16x32_bf16(vf_, pb_, o_acc[d_], 0, 0, 0); \
      } \
    } \
  } while (0)

  STAGE(0, 0);
  uint2 mc = *(const uint2*)(mr);
  uint2 mn;
  fx4_t o_acc[4] = {};
  fx4_t o_l = {};
  for (int tu = 0; tu < 8; ++tu) {
    int tt = 2 * tu;
    __syncthreads();                            // buf0 tile tt ready
    mn = *(const uint2*)(mr + 2 * (tt + 1));
    STAGE(1, tt + 1);                           // in flight during compute
    OCOMP(0, mc);
    __syncthreads();                            // buf1 tile tt+1 ready
    if (tt + 2 < 16) {
      mc = *(const uint2*)(mr + 2 * (tt + 2));
      STAGE(0, tt + 2);
    }
    OCOMP(1, mn);
  }
#undef STAGE
#undef OCOMP
  float iv = 1.0f / o_l[0];
  if (g == 0) linv[(size_t)bh * LQ_ + q0 + qi] = iv;
#pragma unroll
  for (int d = 0; d < 4; ++d) {
    unsigned short pk[4];
#pragma unroll
    for (int r = 0; r < 4; ++r) pk[r] = f2bf(o_acc[d][r] * iv);
    *(us4_t*)&outp[((size_t)(q0 + qi) * B_ + b) * D_ + h * DH_ + d * 16 + 4 * g] = *(us4_t*)&pk[0];
  }
}

// ---------- covgem: 256-THREAD blocks. covpass (bids 0..1023, 4 waves wq2 x wk2) then
// out-proj GEMM (bids 1024..1535, proj3-style 4-wave 128x128 f32-out). (r18/r19 proven) ----------
// Block-size lever saturates HERE: 512-thr (r17) = 106us, 256-thr (r18) = 78us,
// 128-thr (r20) = 92us (FETCH 44->56MB from K re-staging). Do not re-halve.
// XCD pinning: cid = bid exactly (r15 lesson: remaps that break bid%8 cost ~60MB HBM).
__global__ __launch_bounds__(256, 2) void covgem_k(const unsigned short* __restrict__ khm,
    const unsigned short* __restrict__ qhm, const unsigned int* __restrict__ mbits,
    const float* __restrict__ linv, float* __restrict__ cov,
    const unsigned short* __restrict__ outp, const unsigned short* __restrict__ WcT,
    float* __restrict__ out) {
  __shared__ unsigned short smem[2][8192];   // 32KB total, shared by both roles
  int bid = blockIdx.x;
  int t = threadIdx.x, w = t >> 6, l = t & 63, g = l >> 4, qi = l & 15;

  if (bid >= 1024) {
    // ---- out-projection: C(8192,1024) = outp x WcT^T, K=1024, 4 waves x (64x64) ----
    int gid = bid - 1024;                      // 0..511
    const int N = 1024, K = 1024;
    int bx = gid & 63, by = gid >> 6;
    int m0 = bx * 128, n0 = by * 128;
    int wr = w >> 1, wc = w & 1;
    int rl = l >> 2, ul = (l & 3) ^ (rl & 3);
    const unsigned short* Ag = outp + (size_t)(m0 + w * 32 + rl) * K + ul * 8;
    const unsigned short* Bg = WcT + (size_t)(n0 + w * 32 + rl) * K + ul * 8;
    int qx = qi & 3;
    fx4_t acc[4][4] = {};
    const int nk = K / 32;

#define GSTAGE8(PAR, KS) do { \
    gld16(Ag + (size_t)(KS) * 32,          &smem[0][(PAR) * 4096 + (w * 32) * 32]); \
    gld16(Ag + (size_t)(KS) * 32 + 16 * K, &smem[0][(PAR) * 4096 + (w * 32 + 16) * 32]); \
    gld16(Bg + (size_t)(KS) * 32,          &smem[1][(PAR) * 4096 + (w * 32) * 32]); \
    gld16(Bg + (size_t)(KS) * 32 + 16 * K, &smem[1][(PAR) * 4096 + (w * 32 + 16) * 32]); \
  } while (0)

#define GCOMP8(PAR) do { \
    bf16x8_t af_[4], bf_[4]; \
    _Pragma("unroll") for (int mi = 0; mi < 4; ++mi) \
      af_[mi] = *(bf16x8_t*)&smem[0][(PAR) * 4096 + (wr * 64 + mi * 16 + qi) * 32 + ((g ^ qx) * 8)]; \
    _Pragma("unroll") for (int ni = 0; ni < 4; ++ni) \
      bf_[ni] = *(bf16x8_t*)&smem[1][(PAR) * 4096 + (wc * 64 + ni * 16 + qi) * 32 + ((g ^ qx) * 8)]; \
    _Pragma("unroll") for (int mi = 0; mi < 4; ++mi) \
      _Pragma("unroll") for (int ni = 0; ni < 4; ++ni) \
        acc[mi][ni] = __builtin_amdgcn_mfma_f32_16x16x32_bf16(af_[mi], bf_[ni], acc[mi][ni], 0, 0, 0); \
  } while (0)

    GSTAGE8(0, 0);
    for (int ks = 0; ks < nk; ks += 2) {
      __syncthreads();
      if (ks + 1 < nk) GSTAGE8(1, ks + 1);
      GCOMP8(0);
      __syncthreads();
      if (ks + 2 < nk) GSTAGE8(0, ks + 2);
      GCOMP8(1);
    }
#undef GSTAGE8
#undef GCOMP8
#pragma unroll
    for (int mi = 0; mi < 4; ++mi)
#pragma unroll
      for (int ni = 0; ni < 4; ++ni) {
        int row = m0 + wr * 64 + mi * 16 + g * 4;
        int col = n0 + wc * 64 + ni * 16 + qi;
#pragma unroll
        for (int r = 0; r < 4; ++r)
          out[(size_t)(row + r) * N + col] = acc[mi][ni][r];
      }
    return;
  }

  // ---- covpass role: 4 waves, wq in {0,1} (32q each), wk in {0,1} (64k each). ----
  int cid = bid;
  int x = cid & 7;
  int b = x >> 1, keh = x & 1;
  int rest = cid >> 3;
  int ke = keh * 4 + (rest & 3);
  int qt = rest >> 2;
  int q0 = qt * 64;
  int wq = w >> 1, wk = w & 1;
  int qlo = qi & 7;
  int kbase = ke * 128;
  int qA = q0 + 32 * wq + qi;
  int qB = qA + 16;
  int srow = l >> 3, ssub = (l & 7) ^ srow;
  int wo = ke * 4 + wk * 2;                   // this wave's 2 mask words (64 k)
  uint2 MWA = *(const uint2*)&mbits[((size_t)b * LQ_ + qA) * 32 + wo];
  uint2 MWB = *(const uint2*)&mbits[((size_t)b * LQ_ + qB) * 32 + wo];

#define CSTAGE(PAR, ST) do { \
    const unsigned short* kg_ = khm + (size_t)(b * H_ + (ST)) * LK_ * 64 + ssub * 8; \
    _Pragma("unroll") for (int i_ = 0; i_ < 4; ++i_) { \
      int rr_ = w * 32 + i_ * 8; \
      gld16(kg_ + (size_t)(kbase + rr_ + srow) * 64, &smem[PAR][rr_ * 64]); \
    } } while (0)

#define CGLOB(HH, QF, IV) do { \
    const unsigned short* qra_ = qhm + ((size_t)(b * H_ + (HH)) * LQ_ + qA) * 64; \
    const unsigned short* qrb_ = qra_ + 16 * 64; \
    QF[0] = *(const bf16x8_t*)(qra_ + g * 8); QF[1] = *(const bf16x8_t*)(qra_ + 32 + g * 8); \
    QF[2] = *(const bf16x8_t*)(qrb_ + g * 8); QF[3] = *(const bf16x8_t*)(qrb_ + 32 + g * 8); \
    IV[0] = linv[((size_t)b * H_ + (HH)) * LQ_ + qA]; \
    IV[1] = linv[((size_t)b * H_ + (HH)) * LQ_ + qB]; \
  } while (0)

#define CCOMP(PAR, QF, IV) do { \
    unsigned short* Kc_ = &smem[PAR][0]; \
    fx4_t z_ = {0.f, 0.f, 0.f, 0.f}; \
    _Pragma("unroll") for (int ks = 0; ks < 4; ++ks) { \
      int row_ = wk * 64 + 16 * ks + qi; \
      bf16x8_t k0_ = *(bf16x8_t*)&Kc_[row_ * 64 + ((g ^ qlo) * 8)]; \
      bf16x8_t k1_ = *(bf16x8_t*)&Kc_[row_ * 64 + (((4 + g) ^ qlo) * 8)]; \
      __builtin_amdgcn_s_setprio(1); \
      fx4_t sA_ = __builtin_amdgcn_mfma_f32_16x16x32_bf16(k0_, QF[0], z_, 0, 0, 0); \
      sA_ = __builtin_amdgcn_mfma_f32_16x16x32_bf16(k1_, QF[1], sA_, 0, 0, 0); \
      fx4_t sB_ = __builtin_amdgcn_mfma_f32_16x16x32_bf16(k0_, QF[2], z_, 0, 0, 0); \
      sB_ = __builtin_amdgcn_mfma_f32_16x16x32_bf16(k1_, QF[3], sB_, 0, 0, 0); \
      __builtin_amdgcn_s_setprio(0); \
      unsigned int mwa_ = (ks & 2) ? MWA.y : MWA.x; \
      unsigned int mwb_ = (ks & 2) ? MWB.y : MWB.x; \
      int sh_ = (ks & 1) * 16 + 4 * g; \
      _Pragma("unroll") for (int r_ = 0; r_ < 4; ++r_) { \
        float pA_ = __builtin_amdgcn_exp2f(sA_[r_]) * IV[0]; \
        float pB_ = __builtin_amdgcn_exp2f(sB_[r_]) * IV[1]; \
        cacc[0][ks][r_] += ((mwa_ >> (sh_ + r_)) & 1u) ? 0.f : pA_; \
        cacc[1][ks][r_] += ((mwb_ >> (sh_ + r_)) & 1u) ? 0.f : pB_; \
      } \
    } \
  } while (0)

  CSTAGE(0, 0);
  bf16x8_t qc[4], qn[4];
  float ic[2], in_[2];
  fx4_t cacc[2][4] = {};
  CGLOB(0, qc, ic);
  for (int su = 0; su < 8; ++su) {            // 16 head-steps, dbuf, 2 per iter
    int st = 2 * su;
    __syncthreads();
    CSTAGE(1, st + 1);
    CGLOB(st + 1, qn, in_);
    CCOMP(0, qc, ic);
    __syncthreads();
    if (st + 2 < 16) { CSTAGE(0, st + 2); CGLOB(st + 2, qc, ic); }
    CCOMP(1, qn, in_);
  }
#undef CSTAGE
#undef CGLOB
#undef CCOMP
  int ko = kbase + wk * 64;
#pragma unroll
  for (int ks = 0; ks < 4; ++ks) {
    fx4_t wA = { cacc[0][ks][0] * 0.0625f, cacc[0][ks][1] * 0.0625f,
                 cacc[0][ks][2] * 0.0625f, cacc[0][ks][3] * 0.0625f };
    fx4_t wB = { cacc[1][ks][0] * 0.0625f, cacc[1][ks][1] * 0.0625f,
                 cacc[1][ks][2] * 0.0625f, cacc[1][ks][3] * 0.0625f };
    *(fx4_t*)(cov + ((size_t)b * LQ_ + qA) * LK_ + ko + ks * 16 + 4 * g) = wA;
    *(fx4_t*)(cov + ((size_t)b * LQ_ + qB) * LK_ + ko + ks * 16 + 4 * g) = wB;
  }
}

extern "C" void kernel_launch(void* const* d_in, const int* in_sizes, int n_in,
                              void* d_out, int out_size, void* d_ws, size_t ws_size,
                              hipStream_t stream) {
  (void)in_sizes; (void)n_in; (void)out_size; (void)ws_size;
  const float* query = (const float*)d_in[0];
  const float* key   = (const float*)d_in[1];
  // d_in[2] (value) intentionally unused: reference projects `key` for both K and V.
  const int* mask = (const int*)d_in[3];
  const float* Wq = (const float*)d_in[4];
  const float* Wk = (const float*)d_in[5];
  const float* Wv = (const float*)d_in[6];
  const float* Wc = (const float*)d_in[7];
  float* out = (float*)d_out;
  float* cov = out + (size_t)LQ_ * B_ * D_;

  char* p = (char*)d_ws;
  unsigned short* queryb = (unsigned short*)p; p += (size_t)LQ_ * B_ * D_ * 2;
  unsigned short* keyb   = (unsigned short*)p; p += (size_t)LK_ * B_ * DK_ * 2;
  unsigned short* WqT    = (unsigned short*)p; p += (size_t)D_ * D_ * 2;
  unsigned short* WkT    = (unsigned short*)p; p += (size_t)D_ * DK_ * 2;
  unsigned short* WvT    = (unsigned short*)p; p += (size_t)D_ * DK_ * 2;
  unsigned short* WcT    = (unsigned short*)p; p += (size_t)D_ * D_ * 2;
  unsigned short* qhm    = (unsigned short*)p; p += (size_t)LQ_ * B_ * D_ * 2;  // head-major Q
  unsigned short* khm    = (unsigned short*)p; p += (size_t)LK_ * B_ * D_ * 2;  // head-major K
  unsigned short* vbuf   = (unsigned short*)p; p += (size_t)LK_ * B_ * D_ * 2;
  unsigned short* vbT    = (unsigned short*)p; p += (size_t)LK_ * B_ * D_ * 2;
  unsigned int*   mbits  = (unsigned int*)p;   p += (size_t)B_ * LQ_ * 32 * 4;
  float*          linv   = (float*)p;          p += (size_t)B_ * H_ * LQ_ * 4;
  unsigned short* outp   = queryb;   // reuse: queryb dead after Q projection

  const float QSCALE = 0.125f * 1.44269504088896340736f;

  pre_k<<<dim3(10240), 256, 0, stream>>>(query, key, mask, Wq, Wk, Wv, Wc,
                                         queryb, keyb, mbits, WqT, WkT, WvT, WcT, QSCALE);
  proj3_k<<<dim3(1024), 256, 0, stream>>>(queryb, keyb, WqT, WkT, WvT, qhm, khm, vbuf);
  vtrans_k<<<dim3(LK_ / 64, D_ / 64, B_), 256, 0, stream>>>(vbuf, vbT);
  opass_k<<<dim3(B_ * H_ * (LQ_ / 64)), 256, 0, stream>>>(qhm, khm, vbT, mbits, outp, linv);
  covgem_k<<<dim3(1536), 256, 0, stream>>>(khm, qhm, mbits, linv, cov, outp, WcT, out);
}